// Round 7
// baseline (989.022 us; speedup 1.0000x reference)
//
#include <hip/hip_runtime.h>
#include <math.h>

#define SDIM 64
#define KDIM 16
#define ODIM 32
#define HDIM 30
#define TDIM 200
#define NDIM 512
#define NP 69761
#define EPSV 1e-6f
#define LOG2PIF 1.8378770664093453f

__device__ __forceinline__ float softplusf(float x) {
    return (x > 0.f) ? x + log1pf(expf(-x)) : log1pf(expf(x));
}
__device__ __forceinline__ float wave_max64(float v) {
#pragma unroll
    for (int off = 32; off; off >>= 1) v = fmaxf(v, __shfl_xor(v, off, 64));
    return v;
}
__device__ __forceinline__ float wave_sum64(float v) {
#pragma unroll
    for (int off = 32; off; off >>= 1) v += __shfl_xor(v, off, 64);
    return v;
}
// barrier that waits only on LDS ops — leaves global loads/stores in flight
__device__ __forceinline__ void bar_lds() {
    asm volatile("s_waitcnt lgkmcnt(0)\n\ts_barrier" ::: "memory");
}

// ---------------- kernel 1: per-n parameter transforms ----------------
__global__ __launch_bounds__(256) void transform_kernel(
    const float* __restrict__ theta, float* __restrict__ invstd,
    float* __restrict__ c0, float* __restrict__ ent,
    float* __restrict__ logC, float* __restrict__ Dws,
    float* __restrict__ pdfws)
{
    __shared__ float ls[SDIM * 33];
    const int n = blockIdx.x, tid = threadIdx.x;
    const float* thn = theta + (size_t)n * NP;

    for (int idx = tid; idx < SDIM * ODIM; idx += 256) {
        float x = thn[2048 + idx];
        float sp = softplusf(x) + EPSV;            // A_std
        invstd[(size_t)n * SDIM * ODIM + idx] = 1.f / sp;
        int s = idx >> 5, oo = idx & 31;
        ls[s * 33 + oo] = logf(sp);
    }
    __syncthreads();

    const int wave = tid >> 6, lane = tid & 63;
    if (wave == 0) {                                // c0, ent per state s
        float sum = 0.f;
#pragma unroll
        for (int oo = 0; oo < ODIM; ++oo) sum += ls[lane * 33 + oo];
        c0[n * SDIM + lane]  = -sum - 16.f * LOG2PIF;
        ent[n * SDIM + lane] =  sum + 32.f * (0.5f + 0.5f * LOG2PIF);
    } else if (wave == 1) {                         // log(C + eps)
        float x = thn[69632 + lane];
        float m = wave_max64(x);
        float e = expf(x - m);
        float ssum = wave_sum64(e);
        logC[n * SDIM + lane] = logf(e / ssum + EPSV);
    } else if (wave == 2) {                         // D = softmax(tD)
        float x = thn[69696 + lane];
        float m = wave_max64(x);
        float e = expf(x - m);
        float ssum = wave_sum64(e);
        Dws[n * SDIM + lane] = e / ssum;
    } else {                                        // truncated poisson pdf
        float tt = thn[69760];
        float tau = 60.f / (1.f + expf(-tt)) + 1.f;
        float p = 0.f;
        if (lane < HDIM)
            p = expf((float)lane * logf(tau) - tau - lgammaf((float)lane + 1.f));
        float ssum = wave_sum64(p);
        if (lane < HDIM) pdfws[n * HDIM + lane] = p / ssum;
    }
}

// ------------- kernel 2: per-row B softmax stats (lse) + reward r -------------
__global__ __launch_bounds__(256) void row_stats_kernel(
    const float* __restrict__ theta, const float* __restrict__ logC,
    const float* __restrict__ ent, float* __restrict__ lse,
    float* __restrict__ rws)
{
    const int gw = blockIdx.x * 4 + (threadIdx.x >> 6);  // global row (n,k,i)
    const int lane = threadIdx.x & 63;
    const int n = gw >> 10, rl = gw & 1023;
    float x = theta[(size_t)n * NP + 4096 + (size_t)rl * 64 + lane];
    float m = wave_max64(x);
    float e = expf(x - m);
    float ssum = wave_sum64(e);
    float Bj = e / ssum;
    float contrib = Bj * (logf(Bj + EPSV) - logC[n * SDIM + lane] + ent[n * SDIM + lane]);
    contrib = wave_sum64(contrib);
    if (lane == 0) {
        lse[gw] = m + logf(ssum);
        rws[gw] = -contrib;
    }
}

// ------- kernel 3: belief time-scan, ONE WAVE per n, zero barriers -------
// lane j owns column j of B_a (er[64] regs); b broadcast via LDS; depth-1
// prefetch of next step's raw logits into 64 more regs.
__global__ __launch_bounds__(64) void belief1w_kernel(
    const float* __restrict__ o, const int* __restrict__ a,
    const float* __restrict__ theta, const float* __restrict__ lse,
    const float* __restrict__ invstd, const float* __restrict__ c0g,
    const float* __restrict__ Dws,
    float* __restrict__ out_b, float* __restrict__ out_lp)
{
    __shared__ float o_s[TDIM * ODIM];       // 25.6 KB
    __shared__ int   a_s[TDIM];
    __shared__ float lse_s[KDIM * SDIM];     // 4 KB
    __shared__ __align__(16) float b_bc[SDIM];

    const int n = blockIdx.x, lane = threadIdx.x;
    const float* thn = theta + (size_t)n * NP;
    const float* Xn  = thn + 4096;

    for (int idx = lane; idx < TDIM * ODIM; idx += 64)
        o_s[idx] = o[((size_t)(idx >> 5) * NDIM + n) * ODIM + (idx & 31)];
    for (int idx = lane; idx < TDIM; idx += 64)
        a_s[idx] = a[idx * NDIM + n];
    for (int idx = lane; idx < KDIM * SDIM; idx += 64)
        lse_s[idx] = lse[(size_t)n * KDIM * SDIM + idx];

    // per-lane state s = lane: emission params in registers
    float mean_r[ODIM], istd_r[ODIM];
#pragma unroll
    for (int jq = 0; jq < 8; ++jq) {
        float4 mv = *(const float4*)&thn[lane * ODIM + jq * 4];
        float4 iv = *(const float4*)&invstd[((size_t)n * SDIM + lane) * ODIM + jq * 4];
        mean_r[jq * 4 + 0] = mv.x; mean_r[jq * 4 + 1] = mv.y;
        mean_r[jq * 4 + 2] = mv.z; mean_r[jq * 4 + 3] = mv.w;
        istd_r[jq * 4 + 0] = iv.x; istd_r[jq * 4 + 1] = iv.y;
        istd_r[jq * 4 + 2] = iv.z; istd_r[jq * 4 + 3] = iv.w;
    }
    const float c0_r = c0g[n * SDIM + lane];
    float bval = Dws[n * SDIM + lane];
    __syncthreads();   // single wave: cheap; orders LDS staging

    float er[SDIM], raw[SDIM];
    {   // prologue: er = B(a_0) column `lane`; raw = logits(a_1)
        const int a0 = a_s[0];
        const float* X0 = Xn + (size_t)a0 * SDIM * SDIM;
        const float* l0 = &lse_s[a0 * SDIM];
#pragma unroll
        for (int i = 0; i < SDIM; ++i) raw[i] = X0[i * SDIM + lane];
#pragma unroll
        for (int i = 0; i < SDIM; ++i) er[i] = __expf(raw[i] - l0[i]);
        const int a1 = a_s[1 < TDIM ? 1 : 0];
        const float* X1 = Xn + (size_t)a1 * SDIM * SDIM;
#pragma unroll
        for (int i = 0; i < SDIM; ++i) raw[i] = X1[i * SDIM + lane];
    }

#pragma unroll 1
    for (int t = 0; t < TDIM; ++t) {
        // broadcast current belief; emit b_seq
        b_bc[lane] = bval;
        out_b[((size_t)t * NDIM + n) * SDIM + lane] = bval;

        // z2 for this lane's state
        float z2a = 0.f, z2b = 0.f;
#pragma unroll
        for (int m = 0; m < ODIM; m += 2) {
            float za = (o_s[t * ODIM + m]     - mean_r[m])     * istd_r[m];
            float zb = (o_s[t * ODIM + m + 1] - mean_r[m + 1]) * istd_r[m + 1];
            z2a += za * za;
            z2b += zb * zb;
        }
        const float z2 = z2a + z2b;

        // matvec: s[lane] = sum_i er[i] * b[i]
        float acc0 = 0.f, acc1 = 0.f, acc2 = 0.f, acc3 = 0.f;
#pragma unroll
        for (int iq = 0; iq < 16; ++iq) {
            const float4 b4 = *(const float4*)&b_bc[iq * 4];
            acc0 += er[iq * 4 + 0] * b4.x;
            acc1 += er[iq * 4 + 1] * b4.y;
            acc2 += er[iq * 4 + 2] * b4.z;
            acc3 += er[iq * 4 + 3] * b4.w;
        }
        const float sv = (acc0 + acc1) + (acc2 + acc3);

        // convert raw -> er for t+1 (er dead after matvec); prefetch t+2
        {
            const int a1 = a_s[(t + 1 < TDIM) ? t + 1 : TDIM - 1];
            const float* l1 = &lse_s[a1 * SDIM];
#pragma unroll
            for (int i = 0; i < SDIM; ++i) er[i] = __expf(raw[i] - l1[i]);
            const int a2 = a_s[(t + 2 < TDIM) ? t + 2 : TDIM - 1];
            const float* X2 = Xn + (size_t)a2 * SDIM * SDIM;
#pragma unroll
            for (int i = 0; i < SDIM; ++i) raw[i] = X2[i * SDIM + lane];
        }

        // joint + softmax + logp_o
        float joint = __logf(sv + EPSV) + c0_r - 0.5f * z2;
        float m = wave_max64(joint);
        float e = __expf(joint - m);
        float S = wave_sum64(e);
        bval = e / S;
        if (lane == 0) out_lp[(size_t)t * NDIM + n] = m + __logf(S);
    }
}

// ------- kernel 4a: VI, thread-owns-row, q streamed to global workspace -------
__global__ __launch_bounds__(512) void vi_kernel(
    const float* __restrict__ theta, const float* __restrict__ lse,
    const float* __restrict__ rws, float* __restrict__ q_ws)
{
    __shared__ float q_lds[KDIM * 68];
    __shared__ __align__(16) float v_lds[68];
    const int n = blockIdx.x, tid = threadIdx.x;
    const float* Xn = theta + (size_t)n * NP + 4096;

    const float l0  = lse[(size_t)n * 1024 + tid];
    const float l1  = lse[(size_t)n * 1024 + 512 + tid];
    const float rr0 = rws[(size_t)n * 1024 + tid];
    const float rr1 = rws[(size_t)n * 1024 + 512 + tid];

    float4 er0[16], er1[16];
    {
        const float* X0 = Xn + (size_t)tid * 64;
        const float* X1 = Xn + (size_t)(512 + tid) * 64;
#pragma unroll
        for (int j = 0; j < 16; ++j) {
            float4 x = *(const float4*)(X0 + j * 4);
            er0[j] = make_float4(__expf(x.x - l0), __expf(x.y - l0),
                                 __expf(x.z - l0), __expf(x.w - l0));
            float4 y = *(const float4*)(X1 + j * 4);
            er1[j] = make_float4(__expf(y.x - l1), __expf(y.y - l1),
                                 __expf(y.z - l1), __expf(y.w - l1));
        }
    }

    float qr0 = rr0, qr1 = rr1;
    float* qw = q_ws + (size_t)n * HDIM * 1024;
    const int kq0 = tid >> 6, iq = tid & 63;
    qw[tid] = qr0;
    qw[512 + tid] = qr1;
    q_lds[kq0 * 68 + iq] = qr0;
    q_lds[(8 + kq0) * 68 + iq] = qr1;
    __syncthreads();

#pragma unroll 1
    for (int h = 1; h < HDIM; ++h) {
        if (tid < 64) {
            float m = -1e30f;
#pragma unroll
            for (int k = 0; k < KDIM; ++k) m = fmaxf(m, q_lds[k * 68 + tid]);
            float s = 0.f;
#pragma unroll
            for (int k = 0; k < KDIM; ++k) s += __expf(q_lds[k * 68 + tid] - m);
            v_lds[tid] = m + __logf(s);
        }
        bar_lds();
        float a0x = 0.f, a0y = 0.f, a0z = 0.f, a0w = 0.f;
        float a1x = 0.f, a1y = 0.f, a1z = 0.f, a1w = 0.f;
#pragma unroll
        for (int jq = 0; jq < 16; ++jq) {
            const float4 v4 = *(const float4*)&v_lds[jq * 4];
            a0x += er0[jq].x * v4.x; a0y += er0[jq].y * v4.y;
            a0z += er0[jq].z * v4.z; a0w += er0[jq].w * v4.w;
            a1x += er1[jq].x * v4.x; a1y += er1[jq].y * v4.y;
            a1z += er1[jq].z * v4.z; a1w += er1[jq].w * v4.w;
        }
        qr0 = rr0 + ((a0x + a0y) + (a0z + a0w));
        qr1 = rr1 + ((a1x + a1y) + (a1z + a1w));
        qw[(size_t)h * 1024 + tid] = qr0;
        qw[(size_t)h * 1024 + 512 + tid] = qr1;
        q_lds[kq0 * 68 + iq] = qr0;
        q_lds[(8 + kq0) * 68 + iq] = qr1;
        bar_lds();
    }
}

// ------- kernel 4b: policy, q staged in two 15-h mega-chunks (5 barriers) -------
#define HCHUNK 15
__global__ __launch_bounds__(256) void policy_kernel(
    const float* __restrict__ q_ws, const float* __restrict__ out_b_g,
    const float* __restrict__ pdfg, float* __restrict__ out_pi)
{
    __shared__ __align__(16) float qt[HCHUNK * KDIM * 68];  // 65,280 B
    __shared__ __align__(16) float bt[32 * 68];             // 8,704 B
    __shared__ float pdf_s[32];

    const int n = blockIdx.y, tch = blockIdx.x, tid = threadIdx.x;
    const int t0 = tch * 32;
    const int nt = (TDIM - t0) < 32 ? (TDIM - t0) : 32;
    const int tc = tid >> 4, kk = tid & 15;
    const float* qn = q_ws + (size_t)n * HDIM * 1024;

    for (int idx = tid; idx < 32 * 16; idx += 256) {
        const int row = idx >> 4, jq = idx & 15;
        float4 bv = make_float4(0.f, 0.f, 0.f, 0.f);
        if (row < nt)
            bv = *(const float4*)&out_b_g[(((size_t)(t0 + row)) * NDIM + n) * SDIM + jq * 4];
        *(float4*)&bt[row * 68 + jq * 4] = bv;
    }
    if (tid < HDIM) pdf_s[tid] = pdfg[n * HDIM + tid];
    __syncthreads();

    float4 bqA[16], bqB[16];
#pragma unroll
    for (int jq = 0; jq < 16; ++jq) {
        bqA[jq] = *(const float4*)&bt[tc * 68 + jq * 4];
        bqB[jq] = *(const float4*)&bt[(tc + 16) * 68 + jq * 4];
    }

    float pikA = 0.f, pikB = 0.f;
#pragma unroll 1
    for (int hc = 0; hc < 2; ++hc) {
        const int hbase = hc * HCHUNK;
        __syncthreads();   // prior chunk's qt reads done
        // stage 15 h of q (15*1024 floats, 15 float4 per thread)
#pragma unroll
        for (int j = 0; j < HCHUNK; ++j) {
            const int idx = tid + j * 256;
            const int hh = idx >> 8, rem = idx & 255;
            const int krow = rem >> 4, jq = rem & 15;
            *(float4*)&qt[(hh * KDIM + krow) * 68 + jq * 4] =
                *(const float4*)&qn[(size_t)(hbase + hh) * 1024 + rem * 4];
        }
        __syncthreads();
#pragma unroll 1
        for (int hh = 0; hh < HCHUNK; ++hh) {
            const float* qr = &qt[(hh * KDIM + kk) * 68];
            float aAx = 0.f, aAy = 0.f, aAz = 0.f, aAw = 0.f;
            float aBx = 0.f, aBy = 0.f, aBz = 0.f, aBw = 0.f;
#pragma unroll
            for (int jq = 0; jq < 16; ++jq) {
                const float4 q4 = *(const float4*)&qr[jq * 4];
                aAx += q4.x * bqA[jq].x; aAy += q4.y * bqA[jq].y;
                aAz += q4.z * bqA[jq].z; aAw += q4.w * bqA[jq].w;
                aBx += q4.x * bqB[jq].x; aBy += q4.y * bqB[jq].y;
                aBz += q4.z * bqB[jq].z; aBw += q4.w * bqB[jq].w;
            }
            float aA = (aAx + aAy) + (aAz + aAw);
            float aB = (aBx + aBy) + (aBz + aBw);
            float mA = aA, mB = aB;
            mA = fmaxf(mA, __shfl_xor(mA, 1, 64));
            mA = fmaxf(mA, __shfl_xor(mA, 2, 64));
            mA = fmaxf(mA, __shfl_xor(mA, 4, 64));
            mA = fmaxf(mA, __shfl_xor(mA, 8, 64));
            mB = fmaxf(mB, __shfl_xor(mB, 1, 64));
            mB = fmaxf(mB, __shfl_xor(mB, 2, 64));
            mB = fmaxf(mB, __shfl_xor(mB, 4, 64));
            mB = fmaxf(mB, __shfl_xor(mB, 8, 64));
            float eA = __expf(aA - mA), eB = __expf(aB - mB);
            float SA = eA, SB = eB;
            SA += __shfl_xor(SA, 1, 64);
            SA += __shfl_xor(SA, 2, 64);
            SA += __shfl_xor(SA, 4, 64);
            SA += __shfl_xor(SA, 8, 64);
            SB += __shfl_xor(SB, 1, 64);
            SB += __shfl_xor(SB, 2, 64);
            SB += __shfl_xor(SB, 4, 64);
            SB += __shfl_xor(SB, 8, 64);
            const float ph = pdf_s[hbase + hh];
            pikA += ph * eA / SA;
            pikB += ph * eB / SB;
        }
    }
    if (tc < nt)
        out_pi[(((size_t)(t0 + tc)) * NDIM + n) * KDIM + kk] = pikA;
    if (tc + 16 < nt)
        out_pi[(((size_t)(t0 + tc + 16)) * NDIM + n) * KDIM + kk] = pikB;
}

// ------- fallback: fused VI+policy (used if ws too small for q_ws) -------
__global__ __launch_bounds__(512) void vi_policy_kernel(
    const float* __restrict__ theta, const float* __restrict__ lse,
    const float* __restrict__ rws, const float* __restrict__ pdfg,
    const float* __restrict__ out_b_g, float* __restrict__ out_pi)
{
    __shared__ __align__(16) float q_s[HDIM * KDIM * 68];
    __shared__ float r_s[KDIM * SDIM];
    __shared__ float lse_s[KDIM * SDIM];
    __shared__ __align__(16) float v_s[SDIM];
    __shared__ __align__(16) float b_lds[64 * 68];
    __shared__ float pdf_s[32];

    const int n = blockIdx.x, tid = threadIdx.x;
    const int wave = tid >> 6, lane = tid & 63;
    const int sub = lane & 15, rq = lane >> 4;
    const float* Xn = theta + (size_t)n * NP + 4096;

    for (int idx = tid; idx < KDIM * SDIM; idx += 512) {
        r_s[idx]   = rws[(size_t)n * KDIM * SDIM + idx];
        lse_s[idx] = lse[(size_t)n * KDIM * SDIM + idx];
    }
    if (tid < HDIM) pdf_s[tid] = pdfg[n * HDIM + tid];
    __syncthreads();

    for (int idx = tid; idx < KDIM * SDIM; idx += 512)
        q_s[(idx >> 6) * 68 + (idx & 63)] = r_s[idx];

    float4 breg[32];
#pragma unroll
    for (int it = 0; it < 32; ++it) {
        const int row = it * 32 + wave * 4 + rq;
        const float* xr = Xn + (size_t)row * SDIM + sub * 4;
        const float l = lse_s[row];
        breg[it] = make_float4(__expf(xr[0] - l), __expf(xr[1] - l),
                               __expf(xr[2] - l), __expf(xr[3] - l));
    }
    bar_lds();

#pragma unroll 1
    for (int h = 1; h < HDIM; ++h) {
        if (tid < SDIM) {
            const int base = (h - 1) * KDIM;
            float m = -1e30f;
#pragma unroll
            for (int k = 0; k < KDIM; ++k) m = fmaxf(m, q_s[(base + k) * 68 + tid]);
            float ssum = 0.f;
#pragma unroll
            for (int k = 0; k < KDIM; ++k) ssum += __expf(q_s[(base + k) * 68 + tid] - m);
            v_s[tid] = m + __logf(ssum);
        }
        bar_lds();
        const float4 v4 = *(const float4*)&v_s[sub * 4];
#pragma unroll
        for (int it = 0; it < 32; ++it) {
            const int row = it * 32 + wave * 4 + rq;
            float acc = breg[it].x * v4.x + breg[it].y * v4.y
                      + breg[it].z * v4.z + breg[it].w * v4.w;
            acc += __shfl_xor(acc, 1, 64);
            acc += __shfl_xor(acc, 2, 64);
            acc += __shfl_xor(acc, 4, 64);
            acc += __shfl_xor(acc, 8, 64);
            if (sub == 0)
                q_s[(h * KDIM + (row >> 6)) * 68 + (row & 63)] = r_s[row] + acc;
        }
        bar_lds();
    }

    const int tc = tid >> 4, kk = tid & 15;
#pragma unroll 1
    for (int t0 = 0; t0 < TDIM; t0 += 64) {
        const int nt = (TDIM - t0) < 64 ? (TDIM - t0) : 64;
        for (int idx = tid; idx < nt * 16; idx += 512) {
            const int row = idx >> 4, jq = idx & 15;
            *(float4*)&b_lds[row * 68 + jq * 4] =
                *(const float4*)&out_b_g[(((size_t)(t0 + row)) * NDIM + n) * SDIM + jq * 4];
        }
        bar_lds();
        const bool vA = tc < nt, vB = (tc + 32) < nt;
        float4 bqA[16], bqB[16];
        if (vA) {
#pragma unroll
            for (int jq = 0; jq < 16; ++jq)
                bqA[jq] = *(const float4*)&b_lds[tc * 68 + jq * 4];
        }
        if (vB) {
#pragma unroll
            for (int jq = 0; jq < 16; ++jq)
                bqB[jq] = *(const float4*)&b_lds[(tc + 32) * 68 + jq * 4];
        }
        float pikA = 0.f, pikB = 0.f;
#pragma unroll 1
        for (int h = 0; h < HDIM; ++h) {
            const float* qr = &q_s[(h * KDIM + kk) * 68];
            float aA = 0.f, aB = 0.f;
#pragma unroll
            for (int jq = 0; jq < 16; ++jq) {
                const float4 qv = *(const float4*)&qr[jq * 4];
                if (vA) aA += qv.x * bqA[jq].x + qv.y * bqA[jq].y
                            + qv.z * bqA[jq].z + qv.w * bqA[jq].w;
                if (vB) aB += qv.x * bqB[jq].x + qv.y * bqB[jq].y
                            + qv.z * bqB[jq].z + qv.w * bqB[jq].w;
            }
            float mA = aA, mB = aB;
            mA = fmaxf(mA, __shfl_xor(mA, 1, 64));
            mA = fmaxf(mA, __shfl_xor(mA, 2, 64));
            mA = fmaxf(mA, __shfl_xor(mA, 4, 64));
            mA = fmaxf(mA, __shfl_xor(mA, 8, 64));
            mB = fmaxf(mB, __shfl_xor(mB, 1, 64));
            mB = fmaxf(mB, __shfl_xor(mB, 2, 64));
            mB = fmaxf(mB, __shfl_xor(mB, 4, 64));
            mB = fmaxf(mB, __shfl_xor(mB, 8, 64));
            float eA = __expf(aA - mA), eB = __expf(aB - mB);
            float SA = eA, SB = eB;
            SA += __shfl_xor(SA, 1, 64);
            SA += __shfl_xor(SA, 2, 64);
            SA += __shfl_xor(SA, 4, 64);
            SA += __shfl_xor(SA, 8, 64);
            SB += __shfl_xor(SB, 1, 64);
            SB += __shfl_xor(SB, 2, 64);
            SB += __shfl_xor(SB, 4, 64);
            SB += __shfl_xor(SB, 8, 64);
            const float ph = pdf_s[h];
            pikA += ph * eA / SA;
            pikB += ph * eB / SB;
        }
        if (vA) out_pi[(((size_t)(t0 + tc)) * NDIM + n) * KDIM + kk] = pikA;
        if (vB) out_pi[(((size_t)(t0 + 32 + tc)) * NDIM + n) * KDIM + kk] = pikB;
        bar_lds();
    }
}

extern "C" void kernel_launch(void* const* d_in, const int* in_sizes, int n_in,
                              void* d_out, int out_size, void* d_ws, size_t ws_size,
                              hipStream_t stream) {
    (void)in_sizes; (void)n_in; (void)out_size;
    const float* o     = (const float*)d_in[0];
    const int*   a     = (const int*)d_in[1];
    const float* theta = (const float*)d_in[2];
    float* out = (float*)d_out;
    float* ws  = (float*)d_ws;

    float* lse    = ws;                                   // N*K*S
    float* rws    = lse    + (size_t)NDIM * KDIM * SDIM;  // N*K*S
    float* invstd = rws    + (size_t)NDIM * KDIM * SDIM;  // N*S*O
    float* c0     = invstd + (size_t)NDIM * SDIM * ODIM;  // N*S
    float* ent    = c0     + (size_t)NDIM * SDIM;         // N*S
    float* logC   = ent    + (size_t)NDIM * SDIM;         // N*S
    float* Dws    = logC   + (size_t)NDIM * SDIM;         // N*S
    float* pdfws  = Dws    + (size_t)NDIM * SDIM;         // N*H
    float* q_ws   = pdfws  + (size_t)NDIM * HDIM;         // N*H*K*S (63 MB)

    const size_t base_floats = (size_t)NDIM * KDIM * SDIM * 2
                             + (size_t)NDIM * SDIM * ODIM
                             + (size_t)NDIM * SDIM * 4
                             + (size_t)NDIM * HDIM;
    const size_t need_bytes = (base_floats + (size_t)NDIM * HDIM * KDIM * SDIM) * 4;

    float* out_pi = out;
    float* out_b  = out + (size_t)TDIM * NDIM * KDIM;
    float* out_lp = out + (size_t)TDIM * NDIM * KDIM + (size_t)TDIM * NDIM * SDIM;

    transform_kernel<<<NDIM, 256, 0, stream>>>(theta, invstd, c0, ent, logC, Dws, pdfws);
    row_stats_kernel<<<(NDIM * KDIM * SDIM) / 4, 256, 0, stream>>>(theta, logC, ent, lse, rws);
    belief1w_kernel<<<NDIM, 64, 0, stream>>>(o, a, theta, lse, invstd, c0, Dws, out_b, out_lp);

    if (ws_size >= need_bytes) {
        vi_kernel<<<NDIM, 512, 0, stream>>>(theta, lse, rws, q_ws);
        dim3 pgrid((TDIM + 31) / 32, NDIM);
        policy_kernel<<<pgrid, 256, 0, stream>>>(q_ws, out_b, pdfws, out_pi);
    } else {
        vi_policy_kernel<<<NDIM, 512, 0, stream>>>(theta, lse, rws, pdfws, out_b, out_pi);
    }
}